// Round 11
// baseline (911.325 us; speedup 1.0000x reference)
//
#include <hip/hip_runtime.h>
#include <hip/hip_fp16.h>
#include <stdint.h>

#define K_DIM 4096
#define N_DIM 11008
#define WPR   512            // packed int32 words per output row
#define NGRP  32             // quant groups per row
#define NKT32 128            // K-tiles of 32

typedef _Float16 half8 __attribute__((ext_vector_type(8)));
typedef float floatx16 __attribute__((ext_vector_type(16)));
typedef float floatx4 __attribute__((ext_vector_type(4)));
union H8 { __half2 h2[4]; half8 v; };

#define GLOAD16(g, l) __builtin_amdgcn_global_load_lds( \
    (const __attribute__((address_space(1))) uint32_t*)(g), \
    (__attribute__((address_space(3))) uint32_t*)(l), 16, 0, 0)

// ============ fragment-major layout for mfma_f32_32x32x16 ============
// 16B unit u = blk32*16384 + (kh>>1)*64 + (kh&1)*32 + r
//   blk32 = row/32 (or col/32), kh = k/8 (0..511), r = row&31
// halves within a unit: (e0,e4,e1,e5,e2,e6,e3,e7) of k-chunk kh
// (A and B share the permutation -> dot products unaffected).

// ---------- pre-pass 1: x f32 -> f16 fragment-major
__global__ __launch_bounds__(256)
void cvt_x2(const float* __restrict__ x, _Float16* __restrict__ xh) {
    const size_t i = (size_t)blockIdx.x * 256 + threadIdx.x;
    const int r  = (int)i & 31;
    const int kh = ((int)(i >> 5)) & 511;
    const int mb = (int)(i >> 14);
    const float4* p = (const float4*)(x + ((size_t)mb * 32 + r) * K_DIM + kh * 8);
    float4 a = p[0], b = p[1];
    H8 h;
    h.h2[0] = __floats2half2_rn(a.x, b.x);
    h.h2[1] = __floats2half2_rn(a.y, b.y);
    h.h2[2] = __floats2half2_rn(a.z, b.z);
    h.h2[3] = __floats2half2_rn(a.w, b.w);
    const size_t u = (size_t)mb * 16384 + (size_t)((kh >> 1) * 64 + (kh & 1) * 32 + r);
    *(half8*)(xh + u * 8) = h.v;
}

// ---------- pre-pass 2: dequant W -> f16 fragment-major
__global__ __launch_bounds__(256)
void deq_w2(const uint32_t* __restrict__ qw, const float* __restrict__ scales,
            const float* __restrict__ biases, _Float16* __restrict__ wh) {
    const size_t i = (size_t)blockIdx.x * 256 + threadIdx.x;
    const int c  = (int)i & 31;
    const int w  = ((int)(i >> 5)) & 511;
    const int nb = (int)(i >> 14);
    const int row = nb * 32 + c;
    const uint32_t u = qw[(size_t)row * WPR + w];
    const int g = w >> 4;
    const __half2 s2 = __half2half2(__float2half(scales[(size_t)row * NGRP + g]));
    const __half2 b2 = __half2half2(__float2half(biases[(size_t)row * NGRP + g]));
    const __half2 c1024 = __float2half2_rn(1024.0f);
    H8 h;
    #pragma unroll
    for (int p = 0; p < 4; ++p) {
        const uint32_t v = ((u >> (4 * p)) & 0x000F000Fu) | 0x64006400u;
        const __half2 q2 = __hsub2(__builtin_bit_cast(__half2, v), c1024);
        h.h2[p] = __hfma2(s2, q2, b2);
    }
    const size_t uo = (size_t)nb * 16384 + (size_t)((w >> 1) * 64 + (w & 1) * 32 + c);
    *(half8*)(wh + uo * 8) = h.v;
}

// ---------- main GEMM: 256x256 tile, BK=32, 8 waves, 32x32x16 MFMA.
// Round-10 ledger (both operands via global_load_lds, 4 LDS buffers 128 KB,
// stage-ahead-3, vmcnt(8)/4/0, ONE barrier per K-tile) with ALL in-body
// lgkmcnt(0)/sched_barrier fences REMOVED: fragment reads are plain C++
// loads, so the compiler emits its own fine-grained counted lgkm waits and
// software-pipelines ds_read latency under the MFMA clusters (m97 behavior;
// m141 showed explicit order-pinning defeats it). vmcnt asm keeps "memory"
// clobber so LDS reads cannot cross the buffer-reuse barrier.
__global__ __launch_bounds__(512, 2)
void qlin14(const _Float16* __restrict__ xh, const _Float16* __restrict__ wh,
            const float* __restrict__ linb, float* __restrict__ out)
{
    __shared__ _Float16 LD[4][16384];   // 4 x 32 KB (A: halves 0..8191, B: 8192..16383)

    const int nwg = gridDim.x;
    int b = blockIdx.x;
    if ((nwg & 7) == 0) b = (b & 7) * (nwg >> 3) + (b >> 3);  // XCD swizzle
    const int NBN = N_DIM / 256;        // 43
    const int bn = b % NBN;
    const int bm = b / NBN;

    const int tid  = threadIdx.x;
    const int lane = tid & 63;
    const int wid  = tid >> 6;          // 0..7
    const int wr   = wid >> 2;          // 0..1 -> 128-row half
    const int wc   = wid & 3;           // 0..3 -> 64-col slice

    const _Float16* aSt = xh + ((size_t)(bm * 8 + wid) * 16384 + (size_t)lane) * 8;
    const _Float16* bSt = wh + ((size_t)(bn * 8 + wid) * 16384 + (size_t)lane) * 8;
    const int ldsW = wid * 1024;        // halves

    floatx16 acc[4][2] = {};

    auto STAGE_A = [&](int kt) {
        const int k = (kt < NKT32) ? kt : 0;        // clamped tail (harmless)
        const size_t off = (size_t)k * 1024;        // halves
        GLOAD16(aSt + off,       &LD[kt & 3][ldsW]);
        GLOAD16(aSt + off + 512, &LD[kt & 3][ldsW + 512]);
    };
    auto STAGE_B = [&](int kt) {
        const int k = (kt < NKT32) ? kt : 0;
        const size_t off = (size_t)k * 1024;
        GLOAD16(bSt + off,       &LD[kt & 3][8192 + ldsW]);
        GLOAD16(bSt + off + 512, &LD[kt & 3][8192 + ldsW + 512]);
    };

    // body kt: issue ALL 12 ds_reads (both k-halves) + 4 stage-issues, then
    // 16 MFMA (compiler schedules lgkm waits), then vmcnt(vm) + barrier.
    auto BODY = [&](int kt, bool stage, int vm) {
        const _Float16* Lb = &LD[kt & 3][0];
        half8 a0[4], b0[2], a1[4], b1[2];
        #pragma unroll
        for (int mf = 0; mf < 4; ++mf)
            a0[mf] = *(const half8*)(Lb + (wr * 4 + mf) * 1024 + lane * 8);
        #pragma unroll
        for (int nf = 0; nf < 2; ++nf)
            b0[nf] = *(const half8*)(Lb + 8192 + (wc * 2 + nf) * 1024 + lane * 8);
        #pragma unroll
        for (int mf = 0; mf < 4; ++mf)
            a1[mf] = *(const half8*)(Lb + (wr * 4 + mf) * 1024 + 512 + lane * 8);
        #pragma unroll
        for (int nf = 0; nf < 2; ++nf)
            b1[nf] = *(const half8*)(Lb + 8192 + (wc * 2 + nf) * 1024 + 512 + lane * 8);
        if (stage) { STAGE_A(kt + 3); STAGE_B(kt + 3); }
        __builtin_amdgcn_s_setprio(1);
        #pragma unroll
        for (int mf = 0; mf < 4; ++mf)
            #pragma unroll
            for (int nf = 0; nf < 2; ++nf)
                acc[mf][nf] = __builtin_amdgcn_mfma_f32_32x32x16_f16(
                    a0[mf], b0[nf], acc[mf][nf], 0, 0, 0);
        #pragma unroll
        for (int mf = 0; mf < 4; ++mf)
            #pragma unroll
            for (int nf = 0; nf < 2; ++nf)
                acc[mf][nf] = __builtin_amdgcn_mfma_f32_32x32x16_f16(
                    a1[mf], b1[nf], acc[mf][nf], 0, 0, 0);
        __builtin_amdgcn_s_setprio(0);
        if (vm == 8)      asm volatile("s_waitcnt vmcnt(8)" ::: "memory");
        else if (vm == 4) asm volatile("s_waitcnt vmcnt(4)" ::: "memory");
        else if (vm == 0) asm volatile("s_waitcnt vmcnt(0)" ::: "memory");
        else              asm volatile("" ::: "memory");
        if (vm >= 0) __builtin_amdgcn_s_barrier();
    };

    // prologue: stage tiles 0,1,2 (12 loads/wave); vmcnt(8) retires tile 0.
    STAGE_A(0); STAGE_B(0);
    STAGE_A(1); STAGE_B(1);
    STAGE_A(2); STAGE_B(2);
    asm volatile("s_waitcnt vmcnt(8)" ::: "memory");
    __builtin_amdgcn_s_barrier();

    for (int kt = 0; kt < NKT32 - 3; ++kt) BODY(kt, true, 8);
    BODY(NKT32 - 3, false, 4);
    BODY(NKT32 - 2, false, 0);
    BODY(NKT32 - 1, false, -1);

    // epilogue: 32x32 C/D layout col = lane&31, row = (reg&3)+8*(reg>>2)+4*(lane>>5)
    const int colb = bn * 256 + wc * 64 + (lane & 31);
    const int rowb = bm * 256 + wr * 128 + 4 * (lane >> 5);
    #pragma unroll
    for (int j = 0; j < 2; ++j) {
        const int col = colb + j * 32;
        const float lb = linb[col];
        #pragma unroll
        for (int i = 0; i < 4; ++i) {
            #pragma unroll
            for (int reg = 0; reg < 16; ++reg) {
                const int row = rowb + i * 32 + (reg & 3) + 8 * (reg >> 2);
                out[(size_t)row * N_DIM + col] = acc[i][j][reg] + lb;
            }
        }
    }
}

// ---------- fallback (round-3 verified): fused-dequant 128x128 2-phase ----------
#define BM 128
#define BN 128
#define BK 64
#define NKT (K_DIM / BK)

__global__ __launch_bounds__(256)
void cvt_x(const float* __restrict__ x, _Float16* __restrict__ xh) {
    size_t i = (size_t)blockIdx.x * blockDim.x + threadIdx.x;
    const float4* p = (const float4*)(x + i * 8);
    float4 a = p[0], b = p[1];
    H8 h;
    h.h2[0] = __floats2half2_rn(a.x, b.x);
    h.h2[1] = __floats2half2_rn(a.y, b.y);
    h.h2[2] = __floats2half2_rn(a.z, b.z);
    h.h2[3] = __floats2half2_rn(a.w, b.w);
    *(half8*)(xh + i * 8) = h.v;
}

__global__ __launch_bounds__(256, 2)
void qlin_f16(const _Float16* __restrict__ xh,
              const uint32_t* __restrict__ qw,
              const float* __restrict__ scales,
              const float* __restrict__ biases,
              const float* __restrict__ linb,
              float* __restrict__ out)
{
    __shared__ _Float16 Asf[2][BM * BK];
    __shared__ _Float16 Bsf[2][BN * BK];

    const int NBN = N_DIM / BN;
    const int bn = blockIdx.x % NBN;
    const int bm = blockIdx.x / NBN;
    const int tid  = threadIdx.x;
    const int lane = tid & 63;
    const int wv   = tid >> 6;
    const int wm   = (wv >> 1) * 64;
    const int wn   = (wv & 1) * 64;

    const int arow = wv * 32 + (lane >> 3);
    const int acs  = ((lane & 7) ^ ((lane >> 3) & 7)) * 8;
    const _Float16* aSrc = xh + (size_t)(bm * BM + arow) * K_DIM + acs;

    const int srow = tid >> 1;
    const int bsel = tid & 1;
    const uint32_t* qB = qw + (size_t)(bn * BN + srow) * WPR + bsel * 4;
    const float*    sB = scales + (size_t)(bn * BN + srow) * NGRP;
    const float*    bB = biases + (size_t)(bn * BN + srow) * NGRP;
    const int bwbase = srow * BK;
    const int bswz   = srow & 7;

    floatx4 acc[4][4] = {};
    uint4 q0, q1; float s0, b0, s1, b1;

    auto LOADB = [&](uint4& qr, float& s, float& bb, int kt) {
        qr = *(const uint4*)(qB + kt * 8);
        s = sB[kt >> 1]; bb = bB[kt >> 1];
    };
    auto GLOADA = [&](int buf, int kt) {
        const _Float16* sp = aSrc + (size_t)kt * BK;
        #pragma unroll
        for (int j = 0; j < 4; ++j)
            GLOAD16(sp + (size_t)j * 8 * K_DIM, &Asf[buf][wv * 2048 + j * 512]);
    };
    auto DEQ = [&](const uint4& qr, float sf, float bf, int buf) {
        const __half2 s2 = __half2half2(__float2half(sf));
        const __half2 b2 = __half2half2(__float2half(bf));
        const __half2 c1024 = __float2half2_rn(1024.0f);
        const uint32_t uws[4] = {qr.x, qr.y, qr.z, qr.w};
        #pragma unroll
        for (int wi = 0; wi < 4; ++wi) {
            const uint32_t u = uws[wi];
            H8 h;
            #pragma unroll
            for (int p = 0; p < 4; ++p) {
                const uint32_t v = ((u >> (4 * p)) & 0x000F000Fu) | 0x64006400u;
                const __half2 q2 = __hsub2(__builtin_bit_cast(__half2, v), c1024);
                h.h2[p] = __hfma2(s2, q2, b2);
            }
            const int c = bsel * 4 + wi;
            *(half8*)&Bsf[buf][bwbase + ((c ^ bswz) * 8)] = h.v;
        }
    };
    const int fr = lane & 15;
    const int kq = lane >> 4;
    auto COMPUTE = [&](int buf) {
        const _Float16* Ab = &Asf[buf][0];
        const _Float16* Bb = &Bsf[buf][0];
        #pragma unroll
        for (int ks = 0; ks < 2; ++ks) {
            half8 af[4], bf[4];
            const int csx = ks * 4 + kq;
            #pragma unroll
            for (int i = 0; i < 4; ++i) {
                const int r = wm + i * 16 + fr;
                af[i] = *(const half8*)(Ab + r * BK + ((csx ^ (r & 7)) * 8));
            }
            #pragma unroll
            for (int i = 0; i < 4; ++i) {
                const int r = wn + i * 16 + fr;
                bf[i] = *(const half8*)(Bb + r * BK + ((csx ^ (r & 7)) * 8));
            }
            #pragma unroll
            for (int mf = 0; mf < 4; ++mf)
                #pragma unroll
                for (int nf = 0; nf < 4; ++nf)
                    acc[mf][nf] = __builtin_amdgcn_mfma_f32_16x16x32_f16(
                        af[mf], bf[nf], acc[mf][nf], 0, 0, 0);
        }
    };

    LOADB(q0, s0, b0, 0);
    GLOADA(0, 0);
    DEQ(q0, s0, b0, 0);
    LOADB(q0, s0, b0, 1);
    __syncthreads();
    for (int kt = 0; kt < NKT; kt += 2) {
        GLOADA(1, kt + 1);
        if (kt + 2 < NKT) LOADB(q1, s1, b1, kt + 2);
        DEQ(q0, s0, b0, 1);
        COMPUTE(0);
        __syncthreads();
        if (kt + 2 < NKT) {
            GLOADA(0, kt + 2);
            if (kt + 3 < NKT) LOADB(q0, s0, b0, kt + 3);
            DEQ(q1, s1, b1, 0);
        }
        COMPUTE(1);
        if (kt + 2 < NKT) __syncthreads();
    }
    const int rb = bm * BM + wm + ((lane >> 4) << 2);
    const int cb = bn * BN + wn + (lane & 15);
    #pragma unroll
    for (int nf = 0; nf < 4; ++nf) {
        const int col = cb + nf * 16;
        const float lb = linb[col];
        #pragma unroll
        for (int mf = 0; mf < 4; ++mf) {
            const int row = rb + mf * 16;
            #pragma unroll
            for (int j = 0; j < 4; ++j)
                out[(size_t)(row + j) * N_DIM + col] = acc[mf][nf][j] + lb;
        }
    }
}

extern "C" void kernel_launch(void* const* d_in, const int* in_sizes, int n_in,
                              void* d_out, int out_size, void* d_ws, size_t ws_size,
                              hipStream_t stream) {
    const float*    x      = (const float*)d_in[0];
    const uint32_t* qw     = (const uint32_t*)d_in[1];
    const float*    scales = (const float*)d_in[2];
    const float*    biases = (const float*)d_in[3];
    const float*    linb   = (const float*)d_in[4];
    float*          out    = (float*)d_out;

    const int M = in_sizes[0] / K_DIM;                      // 8192
    const size_t needX = (size_t)M * K_DIM * sizeof(_Float16);
    const size_t needW = (size_t)N_DIM * K_DIM * sizeof(_Float16);

    if (ws_size >= needX + needW && (M % 256) == 0) {
        _Float16* xh = (_Float16*)d_ws;
        _Float16* wh = xh + (size_t)M * K_DIM;
        cvt_x2<<<(unsigned)((size_t)M * 512 / 256), 256, 0, stream>>>(x, xh);
        deq_w2<<<(unsigned)((size_t)N_DIM * 512 / 256), 256, 0, stream>>>(qw, scales, biases, wh);
        dim3 grid((M / 256) * (N_DIM / 256));               // 32*43 = 1376
        qlin14<<<grid, 512, 0, stream>>>(xh, wh, linb, out);
    } else if (ws_size >= needX && (M % BM) == 0) {
        _Float16* xh = (_Float16*)d_ws;
        cvt_x<<<(unsigned)((size_t)M * K_DIM / 8 / 256), 256, 0, stream>>>(x, xh);
        dim3 grid((M / BM) * (N_DIM / BN));
        qlin_f16<<<grid, 256, 0, stream>>>(xh, qw, scales, biases, linb, out);
    }
}

// Round 12
// 853.809 us; speedup vs baseline: 1.0674x; 1.0674x over previous
//
#include <hip/hip_runtime.h>
#include <hip/hip_fp16.h>
#include <stdint.h>

#define K_DIM 4096
#define N_DIM 11008
#define WPR   512            // packed int32 words per output row
#define NGRP  32             // quant groups per row
#define NKT32 128            // K-tiles of 32

typedef _Float16 half8 __attribute__((ext_vector_type(8)));
typedef float floatx16 __attribute__((ext_vector_type(16)));
typedef float floatx4 __attribute__((ext_vector_type(4)));
union H8 { __half2 h2[4]; half8 v; };

#define GLOAD16(g, l) __builtin_amdgcn_global_load_lds( \
    (const __attribute__((address_space(1))) uint32_t*)(g), \
    (__attribute__((address_space(3))) uint32_t*)(l), 16, 0, 0)

// ============ fragment-major layout for mfma_f32_32x32x16 ============
// 16B unit u = blk32*16384 + (kh>>1)*64 + (kh&1)*32 + r
//   blk32 = row/32 (or col/32), kh = k/8 (0..511), r = row&31
// halves within a unit: (e0,e4,e1,e5,e2,e6,e3,e7) of k-chunk kh
// (A and B share the permutation -> dot products unaffected).

// ---------- pre-pass 1: x f32 -> f16 fragment-major
__global__ __launch_bounds__(256)
void cvt_x2(const float* __restrict__ x, _Float16* __restrict__ xh) {
    const size_t i = (size_t)blockIdx.x * 256 + threadIdx.x;
    const int r  = (int)i & 31;
    const int kh = ((int)(i >> 5)) & 511;
    const int mb = (int)(i >> 14);
    const float4* p = (const float4*)(x + ((size_t)mb * 32 + r) * K_DIM + kh * 8);
    float4 a = p[0], b = p[1];
    H8 h;
    h.h2[0] = __floats2half2_rn(a.x, b.x);
    h.h2[1] = __floats2half2_rn(a.y, b.y);
    h.h2[2] = __floats2half2_rn(a.z, b.z);
    h.h2[3] = __floats2half2_rn(a.w, b.w);
    const size_t u = (size_t)mb * 16384 + (size_t)((kh >> 1) * 64 + (kh & 1) * 32 + r);
    *(half8*)(xh + u * 8) = h.v;
}

// ---------- pre-pass 2: dequant W -> f16 fragment-major
__global__ __launch_bounds__(256)
void deq_w2(const uint32_t* __restrict__ qw, const float* __restrict__ scales,
            const float* __restrict__ biases, _Float16* __restrict__ wh) {
    const size_t i = (size_t)blockIdx.x * 256 + threadIdx.x;
    const int c  = (int)i & 31;
    const int w  = ((int)(i >> 5)) & 511;
    const int nb = (int)(i >> 14);
    const int row = nb * 32 + c;
    const uint32_t u = qw[(size_t)row * WPR + w];
    const int g = w >> 4;
    const __half2 s2 = __half2half2(__float2half(scales[(size_t)row * NGRP + g]));
    const __half2 b2 = __half2half2(__float2half(biases[(size_t)row * NGRP + g]));
    const __half2 c1024 = __float2half2_rn(1024.0f);
    H8 h;
    #pragma unroll
    for (int p = 0; p < 4; ++p) {
        const uint32_t v = ((u >> (4 * p)) & 0x000F000Fu) | 0x64006400u;
        const __half2 q2 = __hsub2(__builtin_bit_cast(__half2, v), c1024);
        h.h2[p] = __hfma2(s2, q2, b2);
    }
    const size_t uo = (size_t)nb * 16384 + (size_t)((w >> 1) * 64 + (w & 1) * 32 + c);
    *(half8*)(wh + uo * 8) = h.v;
}

// ---------- main GEMM: 256x256 tile, BK=32, 8 waves, 32x32x16 MFMA.
// Register-level tile pipeline on the round-9 ledger:
//   body kt: {12 ds_read of tile kt+1 -> nxt regs} || {4 stage-issues kt+3};
//            16 MFMA on CUR regs (no lgkm wait needed - resident);
//            vmcnt(4) [retires tiles kt+1 AND kt+2] + barrier.
// buf[kt+1] is certified one body early, so ds_read(next) overlaps MFMA(cur)
// WITHIN each wave - no reliance on cross-wave anti-phasing.
__global__ __launch_bounds__(512)
void qlin15(const _Float16* __restrict__ xh, const _Float16* __restrict__ wh,
            const float* __restrict__ linb, float* __restrict__ out)
{
    __shared__ _Float16 LD[4][16384];   // 4 x 32 KB (A: halves 0..8191, B: 8192..16383)

    const int nwg = gridDim.x;
    int b = blockIdx.x;
    if ((nwg & 7) == 0) b = (b & 7) * (nwg >> 3) + (b >> 3);  // XCD swizzle
    const int NBN = N_DIM / 256;        // 43
    const int bn = b % NBN;
    const int bm = b / NBN;

    const int tid  = threadIdx.x;
    const int lane = tid & 63;
    const int wid  = tid >> 6;          // 0..7
    const int wr   = wid >> 2;          // 0..1 -> 128-row half
    const int wc   = wid & 3;           // 0..3 -> 64-col slice

    const _Float16* aSt = xh + ((size_t)(bm * 8 + wid) * 16384 + (size_t)lane) * 8;
    const _Float16* bSt = wh + ((size_t)(bn * 8 + wid) * 16384 + (size_t)lane) * 8;
    const int ldsW = wid * 1024;        // halves

    floatx16 acc[4][2] = {};

    auto STAGE = [&](int kt) {
        const size_t off = (size_t)kt * 1024;       // halves
        GLOAD16(aSt + off,       &LD[kt & 3][ldsW]);
        GLOAD16(aSt + off + 512, &LD[kt & 3][ldsW + 512]);
        GLOAD16(bSt + off,       &LD[kt & 3][8192 + ldsW]);
        GLOAD16(bSt + off + 512, &LD[kt & 3][8192 + ldsW + 512]);
    };

    // frag layout: f[0..3]=A half0, f[4..5]=B half0, f[6..9]=A half1, f[10..11]=B half1
    auto RD = [&](half8* f, int kt) {
        const _Float16* Lb = &LD[kt & 3][0];
        #pragma unroll
        for (int mf = 0; mf < 4; ++mf) {
            f[mf]     = *(const half8*)(Lb + (wr * 4 + mf) * 1024 + lane * 8);
            f[6 + mf] = *(const half8*)(Lb + (wr * 4 + mf) * 1024 + 512 + lane * 8);
        }
        #pragma unroll
        for (int nf = 0; nf < 2; ++nf) {
            f[4 + nf]  = *(const half8*)(Lb + 8192 + (wc * 2 + nf) * 1024 + lane * 8);
            f[10 + nf] = *(const half8*)(Lb + 8192 + (wc * 2 + nf) * 1024 + 512 + lane * 8);
        }
    };
    auto MM = [&](const half8* f) {
        __builtin_amdgcn_s_setprio(1);
        #pragma unroll
        for (int mf = 0; mf < 4; ++mf)
            #pragma unroll
            for (int nf = 0; nf < 2; ++nf)
                acc[mf][nf] = __builtin_amdgcn_mfma_f32_32x32x16_f16(
                    f[mf], f[4 + nf], acc[mf][nf], 0, 0, 0);
        #pragma unroll
        for (int mf = 0; mf < 4; ++mf)
            #pragma unroll
            for (int nf = 0; nf < 2; ++nf)
                acc[mf][nf] = __builtin_amdgcn_mfma_f32_32x32x16_f16(
                    f[6 + mf], f[10 + nf], acc[mf][nf], 0, 0, 0);
        __builtin_amdgcn_s_setprio(0);
    };
    // body kt: read next tile's frags, stage kt+3, MFMA current, vmcnt+barrier
    auto BODY = [&](int kt, const half8* cur, half8* nxt, bool stage, int vm) {
        RD(nxt, kt + 1);
        if (stage) STAGE(kt + 3);
        MM(cur);
        if (vm == 4)      asm volatile("s_waitcnt vmcnt(4)" ::: "memory");
        else if (vm == 0) asm volatile("s_waitcnt vmcnt(0)" ::: "memory");
        if (vm >= 0) __builtin_amdgcn_s_barrier();
    };

    // prologue: stage tiles 0,1,2; vmcnt(4) retires tiles 0 AND 1; read tile 0.
    STAGE(0); STAGE(1); STAGE(2);
    asm volatile("s_waitcnt vmcnt(4)" ::: "memory");
    __builtin_amdgcn_s_barrier();

    half8 f0[12], f1[12];
    RD(f0, 0);

    for (int kt = 0; kt < 124; kt += 2) {
        BODY(kt,     f0, f1, true, 4);
        BODY(kt + 1, f1, f0, true, 4);
    }
    BODY(124, f0, f1, true, 4);     // stages tile 127; retires 126, leaves 127
    BODY(125, f1, f0, false, 0);    // retires tile 127
    BODY(126, f0, f1, false, -1);   // reads tile 127 frags; no sync needed
    MM(f1);                         // tile 127

    // epilogue: 32x32 C/D layout col = lane&31, row = (reg&3)+8*(reg>>2)+4*(lane>>5)
    const int colb = bn * 256 + wc * 64 + (lane & 31);
    const int rowb = bm * 256 + wr * 128 + 4 * (lane >> 5);
    #pragma unroll
    for (int j = 0; j < 2; ++j) {
        const int col = colb + j * 32;
        const float lb = linb[col];
        #pragma unroll
        for (int i = 0; i < 4; ++i) {
            #pragma unroll
            for (int reg = 0; reg < 16; ++reg) {
                const int row = rowb + i * 32 + (reg & 3) + 8 * (reg >> 2);
                out[(size_t)row * N_DIM + col] = acc[i][j][reg] + lb;
            }
        }
    }
}

// ---------- fallback (round-3 verified): fused-dequant 128x128 2-phase ----------
#define BM 128
#define BN 128
#define BK 64
#define NKT (K_DIM / BK)

__global__ __launch_bounds__(256)
void cvt_x(const float* __restrict__ x, _Float16* __restrict__ xh) {
    size_t i = (size_t)blockIdx.x * blockDim.x + threadIdx.x;
    const float4* p = (const float4*)(x + i * 8);
    float4 a = p[0], b = p[1];
    H8 h;
    h.h2[0] = __floats2half2_rn(a.x, b.x);
    h.h2[1] = __floats2half2_rn(a.y, b.y);
    h.h2[2] = __floats2half2_rn(a.z, b.z);
    h.h2[3] = __floats2half2_rn(a.w, b.w);
    *(half8*)(xh + i * 8) = h.v;
}

__global__ __launch_bounds__(256, 2)
void qlin_f16(const _Float16* __restrict__ xh,
              const uint32_t* __restrict__ qw,
              const float* __restrict__ scales,
              const float* __restrict__ biases,
              const float* __restrict__ linb,
              float* __restrict__ out)
{
    __shared__ _Float16 Asf[2][BM * BK];
    __shared__ _Float16 Bsf[2][BN * BK];

    const int NBN = N_DIM / BN;
    const int bn = blockIdx.x % NBN;
    const int bm = blockIdx.x / NBN;
    const int tid  = threadIdx.x;
    const int lane = tid & 63;
    const int wv   = tid >> 6;
    const int wm   = (wv >> 1) * 64;
    const int wn   = (wv & 1) * 64;

    const int arow = wv * 32 + (lane >> 3);
    const int acs  = ((lane & 7) ^ ((lane >> 3) & 7)) * 8;
    const _Float16* aSrc = xh + (size_t)(bm * BM + arow) * K_DIM + acs;

    const int srow = tid >> 1;
    const int bsel = tid & 1;
    const uint32_t* qB = qw + (size_t)(bn * BN + srow) * WPR + bsel * 4;
    const float*    sB = scales + (size_t)(bn * BN + srow) * NGRP;
    const float*    bB = biases + (size_t)(bn * BN + srow) * NGRP;
    const int bwbase = srow * BK;
    const int bswz   = srow & 7;

    floatx4 acc[4][4] = {};
    uint4 q0, q1; float s0, b0, s1, b1;

    auto LOADB = [&](uint4& qr, float& s, float& bb, int kt) {
        qr = *(const uint4*)(qB + kt * 8);
        s = sB[kt >> 1]; bb = bB[kt >> 1];
    };
    auto GLOADA = [&](int buf, int kt) {
        const _Float16* sp = aSrc + (size_t)kt * BK;
        #pragma unroll
        for (int j = 0; j < 4; ++j)
            GLOAD16(sp + (size_t)j * 8 * K_DIM, &Asf[buf][wv * 2048 + j * 512]);
    };
    auto DEQ = [&](const uint4& qr, float sf, float bf, int buf) {
        const __half2 s2 = __half2half2(__float2half(sf));
        const __half2 b2 = __half2half2(__float2half(bf));
        const __half2 c1024 = __float2half2_rn(1024.0f);
        const uint32_t uws[4] = {qr.x, qr.y, qr.z, qr.w};
        #pragma unroll
        for (int wi = 0; wi < 4; ++wi) {
            const uint32_t u = uws[wi];
            H8 h;
            #pragma unroll
            for (int p = 0; p < 4; ++p) {
                const uint32_t v = ((u >> (4 * p)) & 0x000F000Fu) | 0x64006400u;
                const __half2 q2 = __hsub2(__builtin_bit_cast(__half2, v), c1024);
                h.h2[p] = __hfma2(s2, q2, b2);
            }
            const int c = bsel * 4 + wi;
            *(half8*)&Bsf[buf][bwbase + ((c ^ bswz) * 8)] = h.v;
        }
    };
    const int fr = lane & 15;
    const int kq = lane >> 4;
    auto COMPUTE = [&](int buf) {
        const _Float16* Ab = &Asf[buf][0];
        const _Float16* Bb = &Bsf[buf][0];
        #pragma unroll
        for (int ks = 0; ks < 2; ++ks) {
            half8 af[4], bf[4];
            const int csx = ks * 4 + kq;
            #pragma unroll
            for (int i = 0; i < 4; ++i) {
                const int r = wm + i * 16 + fr;
                af[i] = *(const half8*)(Ab + r * BK + ((csx ^ (r & 7)) * 8));
            }
            #pragma unroll
            for (int i = 0; i < 4; ++i) {
                const int r = wn + i * 16 + fr;
                bf[i] = *(const half8*)(Bb + r * BK + ((csx ^ (r & 7)) * 8));
            }
            #pragma unroll
            for (int mf = 0; mf < 4; ++mf)
                #pragma unroll
                for (int nf = 0; nf < 4; ++nf)
                    acc[mf][nf] = __builtin_amdgcn_mfma_f32_16x16x32_f16(
                        af[mf], bf[nf], acc[mf][nf], 0, 0, 0);
        }
    };

    LOADB(q0, s0, b0, 0);
    GLOADA(0, 0);
    DEQ(q0, s0, b0, 0);
    LOADB(q0, s0, b0, 1);
    __syncthreads();
    for (int kt = 0; kt < NKT; kt += 2) {
        GLOADA(1, kt + 1);
        if (kt + 2 < NKT) LOADB(q1, s1, b1, kt + 2);
        DEQ(q0, s0, b0, 1);
        COMPUTE(0);
        __syncthreads();
        if (kt + 2 < NKT) {
            GLOADA(0, kt + 2);
            if (kt + 3 < NKT) LOADB(q0, s0, b0, kt + 3);
            DEQ(q1, s1, b1, 0);
        }
        COMPUTE(1);
        if (kt + 2 < NKT) __syncthreads();
    }
    const int rb = bm * BM + wm + ((lane >> 4) << 2);
    const int cb = bn * BN + wn + (lane & 15);
    #pragma unroll
    for (int nf = 0; nf < 4; ++nf) {
        const int col = cb + nf * 16;
        const float lb = linb[col];
        #pragma unroll
        for (int mf = 0; mf < 4; ++mf) {
            const int row = rb + mf * 16;
            #pragma unroll
            for (int j = 0; j < 4; ++j)
                out[(size_t)(row + j) * N_DIM + col] = acc[mf][nf][j] + lb;
        }
    }
}

extern "C" void kernel_launch(void* const* d_in, const int* in_sizes, int n_in,
                              void* d_out, int out_size, void* d_ws, size_t ws_size,
                              hipStream_t stream) {
    const float*    x      = (const float*)d_in[0];
    const uint32_t* qw     = (const uint32_t*)d_in[1];
    const float*    scales = (const float*)d_in[2];
    const float*    biases = (const float*)d_in[3];
    const float*    linb   = (const float*)d_in[4];
    float*          out    = (float*)d_out;

    const int M = in_sizes[0] / K_DIM;                      // 8192
    const size_t needX = (size_t)M * K_DIM * sizeof(_Float16);
    const size_t needW = (size_t)N_DIM * K_DIM * sizeof(_Float16);

    if (ws_size >= needX + needW && (M % 256) == 0) {
        _Float16* xh = (_Float16*)d_ws;
        _Float16* wh = xh + (size_t)M * K_DIM;
        cvt_x2<<<(unsigned)((size_t)M * 512 / 256), 256, 0, stream>>>(x, xh);
        deq_w2<<<(unsigned)((size_t)N_DIM * 512 / 256), 256, 0, stream>>>(qw, scales, biases, wh);
        dim3 grid((M / 256) * (N_DIM / 256));               // 32*43 = 1376
        qlin15<<<grid, 512, 0, stream>>>(xh, wh, linb, out);
    } else if (ws_size >= needX && (M % BM) == 0) {
        _Float16* xh = (_Float16*)d_ws;
        cvt_x<<<(unsigned)((size_t)M * K_DIM / 8 / 256), 256, 0, stream>>>(x, xh);
        dim3 grid((M / BM) * (N_DIM / BN));
        qlin_f16<<<grid, 256, 0, stream>>>(xh, qw, scales, biases, linb, out);
    }
}

// Round 13
// 780.416 us; speedup vs baseline: 1.1677x; 1.0940x over previous
//
#include <hip/hip_runtime.h>
#include <hip/hip_fp16.h>
#include <stdint.h>

#define K_DIM 4096
#define N_DIM 11008
#define WPR   512            // packed int32 words per output row
#define NGRP  32             // quant groups per row

typedef _Float16 half8 __attribute__((ext_vector_type(8)));
typedef float floatx4 __attribute__((ext_vector_type(4)));
union H8 { __half2 h2[4]; half8 v; };

#define GLOAD16(g, l) __builtin_amdgcn_global_load_lds( \
    (const __attribute__((address_space(1))) uint32_t*)(g), \
    (__attribute__((address_space(3))) uint32_t*)(l), 16, 0, 0)

// ============ fragment-major layout for mfma_f32_16x16x32 ============
// 16B unit u = blk16*8192 + k32*64 + lane, lane = (k8&3)*16 + (row&15)
// halves within unit: 8-chunk interleave (e0,e4,e1,e5,e2,e6,e3,e7).
// A and B share the permutation -> dot products unaffected.
// Prepass write address == thread index (fully contiguous).

// ---------- pre-pass 1: x f32 -> f16 fragment-major-16
__global__ __launch_bounds__(256)
void cvt_x3(const float* __restrict__ x, _Float16* __restrict__ xh) {
    const size_t i = (size_t)blockIdx.x * 256 + threadIdx.x;  // one 8-chunk
    const int r  = (int)i & 15;
    const int kh = ((int)(i >> 4)) & 511;
    const int mb = (int)(i >> 13);
    const float4* p = (const float4*)(x + ((size_t)mb * 16 + r) * K_DIM + kh * 8);
    float4 a = p[0], b = p[1];
    H8 h;
    h.h2[0] = __floats2half2_rn(a.x, b.x);
    h.h2[1] = __floats2half2_rn(a.y, b.y);
    h.h2[2] = __floats2half2_rn(a.z, b.z);
    h.h2[3] = __floats2half2_rn(a.w, b.w);
    *(half8*)(xh + i * 8) = h.v;          // unit index == i
}

// ---------- pre-pass 2: dequant W -> f16 fragment-major-16
__global__ __launch_bounds__(256)
void deq_w3(const uint32_t* __restrict__ qw, const float* __restrict__ scales,
            const float* __restrict__ biases, _Float16* __restrict__ wh) {
    const size_t i = (size_t)blockIdx.x * 256 + threadIdx.x;  // one packed word
    const int c  = (int)i & 15;
    const int w  = ((int)(i >> 4)) & 511;
    const int nb = (int)(i >> 13);
    const int row = nb * 16 + c;
    const uint32_t u = qw[(size_t)row * WPR + w];
    const int g = w >> 4;
    const __half2 s2 = __half2half2(__float2half(scales[(size_t)row * NGRP + g]));
    const __half2 b2 = __half2half2(__float2half(biases[(size_t)row * NGRP + g]));
    const __half2 c1024 = __float2half2_rn(1024.0f);
    H8 h;
    #pragma unroll
    for (int p = 0; p < 4; ++p) {
        const uint32_t v = ((u >> (4 * p)) & 0x000F000Fu) | 0x64006400u;
        const __half2 q2 = __hsub2(__builtin_bit_cast(__half2, v), c1024);
        h.h2[p] = __hfma2(s2, q2, b2);
    }
    *(half8*)(wh + i * 8) = h.v;          // unit index == i
}

// ---------- main GEMM: faithful m201 8-phase template ----------
// 256x256 tile, BK=64, 8 waves (2Mx4N), wave tile 128x64, 16x16x32 MFMA.
// LDS: 2 dbuf x (A 32KB + B 32KB) = 128 KB. Per iter (tiles t=2i, t+1):
// quadrant order (0,0),(0,1),(1,1),(1,0); reads 12/4/8/0 per phase;
// stage slots: {t+1.A0, t+1.A1, t+2.B0, t+2.B1, t+2.A0, t+2.A1, t+3.B0, t+3.B1};
// vmcnt(4) ONLY at phases 4 and 8 (retires exactly the tile needed next).
__global__ __launch_bounds__(512, 2)
void qlin16(const _Float16* __restrict__ xh, const _Float16* __restrict__ wh,
            const float* __restrict__ linb, float* __restrict__ out)
{
    __shared__ _Float16 LD[2][32768];   // [buf][A halves 0..16383 | B 16384..32767]

    const int nwg = gridDim.x;
    int b = blockIdx.x;
    if ((nwg & 7) == 0) b = (b & 7) * (nwg >> 3) + (b >> 3);  // XCD swizzle
    const int NBN = N_DIM / 256;        // 43
    const int bn = b % NBN;
    const int bm = b / NBN;

    const int tid  = threadIdx.x;
    const int lane = tid & 63;
    const int wid  = tid >> 6;          // 0..7
    const int wr   = wid >> 2;          // 0..1 -> 128-row half
    const int wc   = wid & 3;           // 0..3 -> 64-col slice

    // staging bases: thread t handles units q=t and q=t+512 of each half-tile
    const _Float16* aG = xh + ((size_t)(bm * 16 + (tid >> 7)) * 8192
                               + (size_t)(((tid >> 6) & 1) * 64 + (tid & 63))) * 8;
    const _Float16* bG = wh + ((size_t)(bn * 16 + (tid >> 7)) * 8192
                               + (size_t)(((tid >> 6) & 1) * 64 + (tid & 63))) * 8;

    floatx4 acc[8][4] = {};

    auto STG_A = [&](int kt, int h) {    // stage A half-tile h (rows h*128..+127)
        const int k = (kt < 64) ? kt : 0;           // clamped tail (harmless)
        const _Float16* g = aG + ((size_t)h * 65536 + (size_t)k * 128) * 8;
        _Float16* l = &LD[kt & 1][(h * 1024 + tid) * 8];
        GLOAD16(g, l);
        GLOAD16(g + (size_t)262144, l + 4096);      // +4 blk16 / +512 units
    };
    auto STG_B = [&](int kt, int h) {
        const int k = (kt < 64) ? kt : 0;
        const _Float16* g = bG + ((size_t)h * 65536 + (size_t)k * 128) * 8;
        _Float16* l = &LD[kt & 1][16384 + (h * 1024 + tid) * 8];
        GLOAD16(g, l);
        GLOAD16(g + (size_t)262144, l + 4096);
    };

    auto RDA = [&](half8 (&A)[4][2], int buf, int mh) {
        const _Float16* Lb = &LD[buf][0];
        #pragma unroll
        for (int mf = 0; mf < 4; ++mf)
            #pragma unroll
            for (int kc = 0; kc < 2; ++kc)
                A[mf][kc] = *(const half8*)(Lb +
                    (size_t)(((wr * 8 + mh * 4 + mf) * 128 + kc * 64 + lane) * 8));
    };
    auto RDB = [&](half8 (&B)[2][2], int buf, int nh) {
        const _Float16* Lb = &LD[buf][16384];
        #pragma unroll
        for (int nf = 0; nf < 2; ++nf)
            #pragma unroll
            for (int kc = 0; kc < 2; ++kc)
                B[nf][kc] = *(const half8*)(Lb +
                    (size_t)(((wc * 4 + nh * 2 + nf) * 128 + kc * 64 + lane) * 8));
    };
    auto MMQ = [&](const half8 (&A)[4][2], const half8 (&B)[2][2], int mh, int nh) {
        __builtin_amdgcn_s_setprio(1);
        #pragma unroll
        for (int kc = 0; kc < 2; ++kc)
            #pragma unroll
            for (int mf = 0; mf < 4; ++mf)
                #pragma unroll
                for (int nf = 0; nf < 2; ++nf)
                    acc[mh * 4 + mf][nh * 2 + nf] =
                        __builtin_amdgcn_mfma_f32_16x16x32_f16(
                            A[mf][kc], B[nf][kc],
                            acc[mh * 4 + mf][nh * 2 + nf], 0, 0, 0);
        __builtin_amdgcn_s_setprio(0);
        __builtin_amdgcn_sched_barrier(0);
    };

    #define BAR()  __builtin_amdgcn_s_barrier()
    #define LGKM0() do { asm volatile("s_waitcnt lgkmcnt(0)" ::: "memory"); \
                         __builtin_amdgcn_sched_barrier(0); } while (0)

    // prologue: t0 fully + t1.B0,B1 (12 loads); vmcnt(4) retires t0.
    STG_A(0, 0); STG_A(0, 1); STG_B(0, 0); STG_B(0, 1);
    STG_B(1, 0); STG_B(1, 1);
    asm volatile("s_waitcnt vmcnt(4)" ::: "memory");
    BAR();

    half8 A0[4][2], A1[4][2], B0[2][2], B1[2][2];

    for (int i = 0; i < 32; ++i) {
        const int t = 2 * i;
        // ---------------- tile t (buf 0) ----------------
        // ph1: rd A0,B0 (12) | stage (t+1).A0 | q(0,0)
        RDA(A0, 0, 0); RDB(B0, 0, 0); STG_A(t + 1, 0);
        asm volatile("s_waitcnt lgkmcnt(8)" ::: "memory");
        BAR(); LGKM0(); MMQ(A0, B0, 0, 0); BAR();
        // ph2: rd B1 (4) | stage (t+1).A1 | q(0,1)
        RDB(B1, 0, 1); STG_A(t + 1, 1);
        BAR(); LGKM0(); MMQ(A0, B1, 0, 1); BAR();
        // ph3: rd A1 (8) | stage (t+2).B0 | q(1,1)
        RDA(A1, 0, 1); STG_B(t + 2, 0);
        BAR(); LGKM0(); MMQ(A1, B1, 1, 1); BAR();
        // ph4: stage (t+2).B1 | q(1,0) | vmcnt(4): retires t+1 fully
        STG_B(t + 2, 1);
        BAR(); LGKM0(); MMQ(A1, B0, 1, 0);
        asm volatile("s_waitcnt vmcnt(4)" ::: "memory");
        BAR();
        // ---------------- tile t+1 (buf 1) ----------------
        // ph5
        RDA(A0, 1, 0); RDB(B0, 1, 0); STG_A(t + 2, 0);
        asm volatile("s_waitcnt lgkmcnt(8)" ::: "memory");
        BAR(); LGKM0(); MMQ(A0, B0, 0, 0); BAR();
        // ph6
        RDB(B1, 1, 1); STG_A(t + 2, 1);
        BAR(); LGKM0(); MMQ(A0, B1, 0, 1); BAR();
        // ph7
        RDA(A1, 1, 1); STG_B(t + 3, 0);
        BAR(); LGKM0(); MMQ(A1, B1, 1, 1); BAR();
        // ph8: vmcnt(4): retires t+2 fully
        STG_B(t + 3, 1);
        BAR(); LGKM0(); MMQ(A1, B0, 1, 0);
        asm volatile("s_waitcnt vmcnt(4)" ::: "memory");
        BAR();
    }
    asm volatile("s_waitcnt vmcnt(0)" ::: "memory");  // drain clamped tail stages

    // epilogue: 16x16 C/D layout col = lane&15, row = (lane>>4)*4 + j [m89/m91]
    const int colb = bn * 256 + wc * 64 + (lane & 15);
    const int rowb = bm * 256 + wr * 128 + ((lane >> 4) << 2);
    #pragma unroll
    for (int nf = 0; nf < 4; ++nf) {
        const int col = colb + nf * 16;
        const float lb = linb[col];
        #pragma unroll
        for (int mf = 0; mf < 8; ++mf) {
            const int row = rowb + mf * 16;
            #pragma unroll
            for (int j = 0; j < 4; ++j)
                out[(size_t)(row + j) * N_DIM + col] = acc[mf][nf][j] + lb;
        }
    }
    #undef BAR
    #undef LGKM0
}

// ---------- fallback (round-3 verified): fused-dequant 128x128 2-phase ----------
#define BM 128
#define BN 128
#define BK 64
#define NKT (K_DIM / BK)

__global__ __launch_bounds__(256)
void cvt_x(const float* __restrict__ x, _Float16* __restrict__ xh) {
    size_t i = (size_t)blockIdx.x * blockDim.x + threadIdx.x;
    const float4* p = (const float4*)(x + i * 8);
    float4 a = p[0], b = p[1];
    H8 h;
    h.h2[0] = __floats2half2_rn(a.x, b.x);
    h.h2[1] = __floats2half2_rn(a.y, b.y);
    h.h2[2] = __floats2half2_rn(a.z, b.z);
    h.h2[3] = __floats2half2_rn(a.w, b.w);
    *(half8*)(xh + i * 8) = h.v;
}

__global__ __launch_bounds__(256, 2)
void qlin_f16(const _Float16* __restrict__ xh,
              const uint32_t* __restrict__ qw,
              const float* __restrict__ scales,
              const float* __restrict__ biases,
              const float* __restrict__ linb,
              float* __restrict__ out)
{
    __shared__ _Float16 Asf[2][BM * BK];
    __shared__ _Float16 Bsf[2][BN * BK];

    const int NBN = N_DIM / BN;
    const int bn = blockIdx.x % NBN;
    const int bm = blockIdx.x / NBN;
    const int tid  = threadIdx.x;
    const int lane = tid & 63;
    const int wv   = tid >> 6;
    const int wm   = (wv >> 1) * 64;
    const int wn   = (wv & 1) * 64;

    const int arow = wv * 32 + (lane >> 3);
    const int acs  = ((lane & 7) ^ ((lane >> 3) & 7)) * 8;
    const _Float16* aSrc = xh + (size_t)(bm * BM + arow) * K_DIM + acs;

    const int srow = tid >> 1;
    const int bsel = tid & 1;
    const uint32_t* qB = qw + (size_t)(bn * BN + srow) * WPR + bsel * 4;
    const float*    sB = scales + (size_t)(bn * BN + srow) * NGRP;
    const float*    bB = biases + (size_t)(bn * BN + srow) * NGRP;
    const int bwbase = srow * BK;
    const int bswz   = srow & 7;

    floatx4 acc[4][4] = {};
    uint4 q0, q1; float s0, b0, s1, b1;

    auto LOADB = [&](uint4& qr, float& s, float& bb, int kt) {
        qr = *(const uint4*)(qB + kt * 8);
        s = sB[kt >> 1]; bb = bB[kt >> 1];
    };
    auto GLOADA = [&](int buf, int kt) {
        const _Float16* sp = aSrc + (size_t)kt * BK;
        #pragma unroll
        for (int j = 0; j < 4; ++j)
            GLOAD16(sp + (size_t)j * 8 * K_DIM, &Asf[buf][wv * 2048 + j * 512]);
    };
    auto DEQ = [&](const uint4& qr, float sf, float bf, int buf) {
        const __half2 s2 = __half2half2(__float2half(sf));
        const __half2 b2 = __half2half2(__float2half(bf));
        const __half2 c1024 = __float2half2_rn(1024.0f);
        const uint32_t uws[4] = {qr.x, qr.y, qr.z, qr.w};
        #pragma unroll
        for (int wi = 0; wi < 4; ++wi) {
            const uint32_t u = uws[wi];
            H8 h;
            #pragma unroll
            for (int p = 0; p < 4; ++p) {
                const uint32_t v = ((u >> (4 * p)) & 0x000F000Fu) | 0x64006400u;
                const __half2 q2 = __hsub2(__builtin_bit_cast(__half2, v), c1024);
                h.h2[p] = __hfma2(s2, q2, b2);
            }
            const int c = bsel * 4 + wi;
            *(half8*)&Bsf[buf][bwbase + ((c ^ bswz) * 8)] = h.v;
        }
    };
    const int fr = lane & 15;
    const int kq = lane >> 4;
    auto COMPUTE = [&](int buf) {
        const _Float16* Ab = &Asf[buf][0];
        const _Float16* Bb = &Bsf[buf][0];
        #pragma unroll
        for (int ks = 0; ks < 2; ++ks) {
            half8 af[4], bf[4];
            const int csx = ks * 4 + kq;
            #pragma unroll
            for (int i = 0; i < 4; ++i) {
                const int r = wm + i * 16 + fr;
                af[i] = *(const half8*)(Ab + r * BK + ((csx ^ (r & 7)) * 8));
            }
            #pragma unroll
            for (int i = 0; i < 4; ++i) {
                const int r = wn + i * 16 + fr;
                bf[i] = *(const half8*)(Bb + r * BK + ((csx ^ (r & 7)) * 8));
            }
            #pragma unroll
            for (int mf = 0; mf < 4; ++mf)
                #pragma unroll
                for (int nf = 0; nf < 4; ++nf)
                    acc[mf][nf] = __builtin_amdgcn_mfma_f32_16x16x32_f16(
                        af[mf], bf[nf], acc[mf][nf], 0, 0, 0);
        }
    };

    LOADB(q0, s0, b0, 0);
    GLOADA(0, 0);
    DEQ(q0, s0, b0, 0);
    LOADB(q0, s0, b0, 1);
    __syncthreads();
    for (int kt = 0; kt < NKT; kt += 2) {
        GLOADA(1, kt + 1);
        if (kt + 2 < NKT) LOADB(q1, s1, b1, kt + 2);
        DEQ(q0, s0, b0, 1);
        COMPUTE(0);
        __syncthreads();
        if (kt + 2 < NKT) {
            GLOADA(0, kt + 2);
            if (kt + 3 < NKT) LOADB(q0, s0, b0, kt + 3);
            DEQ(q1, s1, b1, 0);
        }
        COMPUTE(1);
        if (kt + 2 < NKT) __syncthreads();
    }
    const int rb = bm * BM + wm + ((lane >> 4) << 2);
    const int cb = bn * BN + wn + (lane & 15);
    #pragma unroll
    for (int nf = 0; nf < 4; ++nf) {
        const int col = cb + nf * 16;
        const float lb = linb[col];
        #pragma unroll
        for (int mf = 0; mf < 4; ++mf) {
            const int row = rb + mf * 16;
            #pragma unroll
            for (int j = 0; j < 4; ++j)
                out[(size_t)(row + j) * N_DIM + col] = acc[mf][nf][j] + lb;
        }
    }
}

extern "C" void kernel_launch(void* const* d_in, const int* in_sizes, int n_in,
                              void* d_out, int out_size, void* d_ws, size_t ws_size,
                              hipStream_t stream) {
    const float*    x      = (const float*)d_in[0];
    const uint32_t* qw     = (const uint32_t*)d_in[1];
    const float*    scales = (const float*)d_in[2];
    const float*    biases = (const float*)d_in[3];
    const float*    linb   = (const float*)d_in[4];
    float*          out    = (float*)d_out;

    const int M = in_sizes[0] / K_DIM;                      // 8192
    const size_t needX = (size_t)M * K_DIM * sizeof(_Float16);
    const size_t needW = (size_t)N_DIM * K_DIM * sizeof(_Float16);

    if (ws_size >= needX + needW && (M % 256) == 0) {
        _Float16* xh = (_Float16*)d_ws;
        _Float16* wh = xh + (size_t)M * K_DIM;
        cvt_x3<<<(unsigned)((size_t)M * K_DIM / 8 / 256), 256, 0, stream>>>(x, xh);
        deq_w3<<<(unsigned)((size_t)N_DIM * WPR / 256), 256, 0, stream>>>(qw, scales, biases, wh);
        dim3 grid((M / 256) * (N_DIM / 256));               // 32*43 = 1376
        qlin16<<<grid, 512, 0, stream>>>(xh, wh, linb, out);
    } else if (ws_size >= needX && (M % BM) == 0) {
        _Float16* xh = (_Float16*)d_ws;
        cvt_x<<<(unsigned)((size_t)M * K_DIM / 8 / 256), 256, 0, stream>>>(x, xh);
        dim3 grid((M / BM) * (N_DIM / BN));
        qlin_f16<<<grid, 256, 0, stream>>>(xh, qw, scales, biases, linb, out);
    }
}

// Round 14
// 461.750 us; speedup vs baseline: 1.9736x; 1.6901x over previous
//
#include <hip/hip_runtime.h>
#include <hip/hip_fp16.h>
#include <stdint.h>

#define K_DIM 4096
#define N_DIM 11008
#define WPR   512            // packed int32 words per output row
#define NGRP  32             // quant groups per row

typedef _Float16 half8 __attribute__((ext_vector_type(8)));
typedef float floatx4 __attribute__((ext_vector_type(4)));
typedef int   intx4  __attribute__((ext_vector_type(4)));
typedef int   intx16 __attribute__((ext_vector_type(16)));
union H8 { __half2 h2[4]; half8 v; };

#define GLOAD16(g, l) __builtin_amdgcn_global_load_lds( \
    (const __attribute__((address_space(1))) uint32_t*)(g), \
    (__attribute__((address_space(3))) uint32_t*)(l), 16, 0, 0)

// ============ fragment-major i8 layout for mfma_i32_32x32x32_i8 ============
// 16B unit u = blk32*8192 + k32*64 + half*32 + (row&31); unit holds the 16
// consecutive i8 k-values [k32*32 + half*16, +16) of one row. A and B share
// the mapping -> HW pairs (half,slot) of A with (half,slot) of B, any
// consistent k-order cancels (same argument as the verified f16 kernels).

static __device__ __forceinline__ uint32_t pack4(int a, int b, int c, int d) {
    return (uint32_t)(a & 255) | ((uint32_t)(b & 255) << 8) |
           ((uint32_t)(c & 255) << 16) | ((uint32_t)(d & 255) << 24);
}

// ---------- pre-pass 1: x f32 -> i8 fragment-major, per-row scale sx
__global__ __launch_bounds__(256)
void cvt_xq(const float* __restrict__ x, int8_t* __restrict__ xq,
            float* __restrict__ sx) {
    const int wid = threadIdx.x >> 6, lane = threadIdx.x & 63;
    const int row = blockIdx.x * 4 + wid;
    const float4* xr = (const float4*)(x + (size_t)row * K_DIM + lane * 64);
    float v[64];
    float amax = 0.f;
    #pragma unroll
    for (int i = 0; i < 16; ++i) {
        float4 f = xr[i];
        v[4*i] = f.x; v[4*i+1] = f.y; v[4*i+2] = f.z; v[4*i+3] = f.w;
        amax = fmaxf(amax, fmaxf(fmaxf(fabsf(f.x), fabsf(f.y)),
                                 fmaxf(fabsf(f.z), fabsf(f.w))));
    }
    #pragma unroll
    for (int m = 32; m; m >>= 1) amax = fmaxf(amax, __shfl_xor(amax, m));
    amax = fmaxf(amax, 1e-20f);
    const float inv = 127.0f / amax;
    uint32_t d[16];
    #pragma unroll
    for (int j = 0; j < 16; ++j)
        d[j] = pack4((int)rintf(v[4*j] * inv),   (int)rintf(v[4*j+1] * inv),
                     (int)rintf(v[4*j+2] * inv), (int)rintf(v[4*j+3] * inv));
    uint4* dst = (uint4*)xq;
    #pragma unroll
    for (int c2 = 0; c2 < 2; ++c2)
        #pragma unroll
        for (int h = 0; h < 2; ++h) {
            const size_t u = (size_t)(row >> 5) * 8192 +
                             (size_t)((lane * 2 + c2) * 64 + h * 32 + (row & 31));
            const int j0 = (c2 * 2 + h) * 4;
            dst[u] = make_uint4(d[j0], d[j0+1], d[j0+2], d[j0+3]);
        }
    if (lane == 0) sx[row] = amax * (1.0f / 127.0f);
}

// ---------- pre-pass 2: dequant W (f32) -> i8 fragment-major, per-row scale sw
__global__ __launch_bounds__(256)
void deq_wq(const uint32_t* __restrict__ qw, const float* __restrict__ scales,
            const float* __restrict__ biases, int8_t* __restrict__ wq,
            float* __restrict__ sw) {
    const int wid = threadIdx.x >> 6, lane = threadIdx.x & 63;
    const int row = blockIdx.x * 4 + wid;
    const uint4* qr = (const uint4*)(qw + (size_t)row * WPR) + lane * 2;
    const uint4 q0 = qr[0], q1 = qr[1];
    const int g = lane >> 1;
    const float s  = scales[(size_t)row * NGRP + g];
    const float bb = biases[(size_t)row * NGRP + g];
    const uint32_t uw[8] = {q0.x, q0.y, q0.z, q0.w, q1.x, q1.y, q1.z, q1.w};
    float v[64];
    float amax = 0.f;
    #pragma unroll
    for (int w8 = 0; w8 < 8; ++w8) {
        const uint32_t u = uw[w8];
        #pragma unroll
        for (int e = 0; e < 8; ++e) {
            const float val = fmaf(s, (float)((u >> (4 * e)) & 15u), bb);
            v[w8 * 8 + e] = val;
            amax = fmaxf(amax, fabsf(val));
        }
    }
    #pragma unroll
    for (int m = 32; m; m >>= 1) amax = fmaxf(amax, __shfl_xor(amax, m));
    amax = fmaxf(amax, 1e-20f);
    const float inv = 127.0f / amax;
    uint32_t d[16];
    #pragma unroll
    for (int j = 0; j < 16; ++j)
        d[j] = pack4((int)rintf(v[4*j] * inv),   (int)rintf(v[4*j+1] * inv),
                     (int)rintf(v[4*j+2] * inv), (int)rintf(v[4*j+3] * inv));
    uint4* dst = (uint4*)wq;
    #pragma unroll
    for (int c2 = 0; c2 < 2; ++c2)
        #pragma unroll
        for (int h = 0; h < 2; ++h) {
            const size_t u = (size_t)(row >> 5) * 8192 +
                             (size_t)((lane * 2 + c2) * 64 + h * 32 + (row & 31));
            const int j0 = (c2 * 2 + h) * 4;
            dst[u] = make_uint4(d[j0], d[j0+1], d[j0+2], d[j0+3]);
        }
    if (lane == 0) sw[row] = amax * (1.0f / 127.0f);
}

// ---------- main GEMM: i8 8-phase (round-13 skeleton, K-tile=128) ----------
// 256x256 tile, 8 waves (2Mx4N), wave 128x64 as 4x2 frags of 32x32.
// LDS: 2 dbuf x (A 32KB + B 32KB) = 128 KB. Per tile (K-128) 4 phases;
// stage slots {t+1.A0, t+1.A1, t+2.B0, t+2.B1}; vmcnt(4) only at ph4.
__global__ __launch_bounds__(512, 2)
void qlin17(const int8_t* __restrict__ xq, const int8_t* __restrict__ wq,
            const float* __restrict__ sx, const float* __restrict__ sw,
            const float* __restrict__ linb, float* __restrict__ out)
{
    __shared__ int8_t LD[2][65536];     // [buf][A bytes 0..32767 | B 32768..65535]

    const int nwg = gridDim.x;
    int b = blockIdx.x;
    if ((nwg & 7) == 0) b = (b & 7) * (nwg >> 3) + (b >> 3);  // XCD swizzle
    const int NBN = N_DIM / 256;        // 43
    const int bn = b % NBN;
    const int bm = b / NBN;

    const int tid  = threadIdx.x;
    const int lane = tid & 63;
    const int wid  = tid >> 6;
    const int wr   = wid >> 2;          // 0..1 -> 128-row half
    const int wc   = wid & 3;           // 0..3 -> 64-col slice

    // staging: thread t -> LDS units (h*1024 + t) and (+512) of the half-tile
    const int8_t* aG = xq + ((size_t)(bm * 8 + (tid >> 8)) * 8192
                             + (size_t)(((tid >> 6) & 3) * 64 + (tid & 63))) * 16;
    const int8_t* bG = wq + ((size_t)(bn * 8 + (tid >> 8)) * 8192
                             + (size_t)(((tid >> 6) & 3) * 64 + (tid & 63))) * 16;

    intx16 acc[4][2] = {};

    auto STG_A = [&](int kt, int h) {    // A half-tile h (blk32s 4h..4h+3)
        const int k = (kt < 32) ? kt : 0;           // clamped tail (audited safe)
        const int8_t* g = aG + (size_t)h * 524288 + (size_t)k * 4096;
        int8_t* l = &LD[kt & 1][(h * 1024 + tid) * 16];
        GLOAD16(g, l);
        GLOAD16(g + 262144, l + 8192);              // +2 blk32 / +512 units
    };
    auto STG_B = [&](int kt, int h) {
        const int k = (kt < 32) ? kt : 0;
        const int8_t* g = bG + (size_t)h * 524288 + (size_t)k * 4096;
        int8_t* l = &LD[kt & 1][32768 + (h * 1024 + tid) * 16];
        GLOAD16(g, l);
        GLOAD16(g + 262144, l + 8192);
    };

    auto RDA = [&](intx4 (&A)[2][4], int buf, int mh) {
        const int8_t* Lb = &LD[buf][0];
        #pragma unroll
        for (int mf = 0; mf < 2; ++mf)
            #pragma unroll
            for (int ks = 0; ks < 4; ++ks)
                A[mf][ks] = *(const intx4*)(Lb +
                    (size_t)(((wr * 4 + mh * 2 + mf) * 256 + ks * 64 + lane) * 16));
    };
    auto RDB = [&](intx4 (&B)[4], int buf, int nh) {
        const int8_t* Lb = &LD[buf][32768];
        #pragma unroll
        for (int ks = 0; ks < 4; ++ks)
            B[ks] = *(const intx4*)(Lb +
                (size_t)(((wc * 2 + nh) * 256 + ks * 64 + lane) * 16));
    };
    auto MMQ = [&](const intx4 (&A)[2][4], const intx4 (&B)[4], int mh, int nh) {
        __builtin_amdgcn_s_setprio(1);
        #pragma unroll
        for (int ks = 0; ks < 4; ++ks)
            #pragma unroll
            for (int mf = 0; mf < 2; ++mf)
                acc[mh * 2 + mf][nh] = __builtin_amdgcn_mfma_i32_32x32x32_i8(
                    A[mf][ks], B[ks], acc[mh * 2 + mf][nh], 0, 0, 0);
        __builtin_amdgcn_s_setprio(0);
        __builtin_amdgcn_sched_barrier(0);
    };

    #define BAR()  __builtin_amdgcn_s_barrier()
    #define LGKM0() do { asm volatile("s_waitcnt lgkmcnt(0)" ::: "memory"); \
                         __builtin_amdgcn_sched_barrier(0); } while (0)

    // prologue: t0 fully + t1.B (12 gloads); vmcnt(4) retires t0.
    STG_A(0, 0); STG_A(0, 1); STG_B(0, 0); STG_B(0, 1);
    STG_B(1, 0); STG_B(1, 1);
    asm volatile("s_waitcnt vmcnt(4)" ::: "memory");
    BAR();

    intx4 Aa[2][4], Ab[2][4], Ba[4], Bb[4];

    for (int t = 0; t < 32; ++t) {
        const int buf = t & 1;
        // ph1: rd A-h0 (8) + B0 (4) | stage (t+1).A0 | q(0,0)
        RDA(Aa, buf, 0); RDB(Ba, buf, 0); STG_A(t + 1, 0);
        asm volatile("s_waitcnt lgkmcnt(8)" ::: "memory");
        BAR(); LGKM0(); MMQ(Aa, Ba, 0, 0); BAR();
        // ph2: rd B1 (4) | stage (t+1).A1 | q(0,1)
        RDB(Bb, buf, 1); STG_A(t + 1, 1);
        BAR(); LGKM0(); MMQ(Aa, Bb, 0, 1); BAR();
        // ph3: rd A-h1 (8) | stage (t+2).B0 | q(1,1)
        RDA(Ab, buf, 1); STG_B(t + 2, 0);
        BAR(); LGKM0(); MMQ(Ab, Bb, 1, 1); BAR();
        // ph4: stage (t+2).B1 | q(1,0) | vmcnt(4): retires t+1 fully
        STG_B(t + 2, 1);
        BAR(); LGKM0(); MMQ(Ab, Ba, 1, 0);
        asm volatile("s_waitcnt vmcnt(4)" ::: "memory");
        BAR();
    }
    asm volatile("s_waitcnt vmcnt(0)" ::: "memory");

    // epilogue: 32x32 C/D layout col = lane&31, row = (reg&3)+8*(reg>>2)+4*(lane>>5)
    const int colb = bn * 256 + wc * 64 + (lane & 31);
    const int rowb = bm * 256 + wr * 128 + 4 * (lane >> 5);
    float swc[2], lbc[2];
    #pragma unroll
    for (int nf = 0; nf < 2; ++nf) {
        swc[nf] = sw[colb + nf * 32];
        lbc[nf] = linb[colb + nf * 32];
    }
    #pragma unroll
    for (int mf = 0; mf < 4; ++mf) {
        #pragma unroll
        for (int reg = 0; reg < 16; ++reg) {
            const int row = rowb + mf * 32 + (reg & 3) + 8 * (reg >> 2);
            const float sxr = sx[row];
            #pragma unroll
            for (int nf = 0; nf < 2; ++nf) {
                const int col = colb + nf * 32;
                out[(size_t)row * N_DIM + col] =
                    (float)acc[mf][nf][reg] * (sxr * swc[nf]) + lbc[nf];
            }
        }
    }
    #undef BAR
    #undef LGKM0
}

// ---------- fallback (round-3 verified): fused-dequant 128x128 2-phase ----------
#define BM 128
#define BN 128
#define BK 64
#define NKT (K_DIM / BK)

__global__ __launch_bounds__(256)
void cvt_x(const float* __restrict__ x, _Float16* __restrict__ xh) {
    size_t i = (size_t)blockIdx.x * blockDim.x + threadIdx.x;
    const float4* p = (const float4*)(x + i * 8);
    float4 a = p[0], b = p[1];
    H8 h;
    h.h2[0] = __floats2half2_rn(a.x, b.x);
    h.h2[1] = __floats2half2_rn(a.y, b.y);
    h.h2[2] = __floats2half2_rn(a.z, b.z);
    h.h2[3] = __floats2half2_rn(a.w, b.w);
    *(half8*)(xh + i * 8) = h.v;
}

__global__ __launch_bounds__(256, 2)
void qlin_f16(const _Float16* __restrict__ xh,
              const uint32_t* __restrict__ qw,
              const float* __restrict__ scales,
              const float* __restrict__ biases,
              const float* __restrict__ linb,
              float* __restrict__ out)
{
    __shared__ _Float16 Asf[2][BM * BK];
    __shared__ _Float16 Bsf[2][BN * BK];

    const int NBN = N_DIM / BN;
    const int bn = blockIdx.x % NBN;
    const int bm = blockIdx.x / NBN;
    const int tid  = threadIdx.x;
    const int lane = tid & 63;
    const int wv   = tid >> 6;
    const int wm   = (wv >> 1) * 64;
    const int wn   = (wv & 1) * 64;

    const int arow = wv * 32 + (lane >> 3);
    const int acs  = ((lane & 7) ^ ((lane >> 3) & 7)) * 8;
    const _Float16* aSrc = xh + (size_t)(bm * BM + arow) * K_DIM + acs;

    const int srow = tid >> 1;
    const int bsel = tid & 1;
    const uint32_t* qB = qw + (size_t)(bn * BN + srow) * WPR + bsel * 4;
    const float*    sB = scales + (size_t)(bn * BN + srow) * NGRP;
    const float*    bB = biases + (size_t)(bn * BN + srow) * NGRP;
    const int bwbase = srow * BK;
    const int bswz   = srow & 7;

    floatx4 acc[4][4] = {};
    uint4 q0, q1; float s0, b0, s1, b1;

    auto LOADB = [&](uint4& qr, float& s, float& bb, int kt) {
        qr = *(const uint4*)(qB + kt * 8);
        s = sB[kt >> 1]; bb = bB[kt >> 1];
    };
    auto GLOADA = [&](int buf, int kt) {
        const _Float16* sp = aSrc + (size_t)kt * BK;
        #pragma unroll
        for (int j = 0; j < 4; ++j)
            GLOAD16(sp + (size_t)j * 8 * K_DIM, &Asf[buf][wv * 2048 + j * 512]);
    };
    auto DEQ = [&](const uint4& qr, float sf, float bf, int buf) {
        const __half2 s2 = __half2half2(__float2half(sf));
        const __half2 b2 = __half2half2(__float2half(bf));
        const __half2 c1024 = __float2half2_rn(1024.0f);
        const uint32_t uws[4] = {qr.x, qr.y, qr.z, qr.w};
        #pragma unroll
        for (int wi = 0; wi < 4; ++wi) {
            const uint32_t u = uws[wi];
            H8 h;
            #pragma unroll
            for (int p = 0; p < 4; ++p) {
                const uint32_t v = ((u >> (4 * p)) & 0x000F000Fu) | 0x64006400u;
                const __half2 q2 = __hsub2(__builtin_bit_cast(__half2, v), c1024);
                h.h2[p] = __hfma2(s2, q2, b2);
            }
            const int c = bsel * 4 + wi;
            *(half8*)&Bsf[buf][bwbase + ((c ^ bswz) * 8)] = h.v;
        }
    };
    const int fr = lane & 15;
    const int kq = lane >> 4;
    auto COMPUTE = [&](int buf) {
        const _Float16* Ab = &Asf[buf][0];
        const _Float16* Bb = &Bsf[buf][0];
        #pragma unroll
        for (int ks = 0; ks < 2; ++ks) {
            half8 af[4], bf[4];
            const int csx = ks * 4 + kq;
            #pragma unroll
            for (int i = 0; i < 4; ++i) {
                const int r = wm + i * 16 + fr;
                af[i] = *(const half8*)(Ab + r * BK + ((csx ^ (r & 7)) * 8));
            }
            #pragma unroll
            for (int i = 0; i < 4; ++i) {
                const int r = wn + i * 16 + fr;
                bf[i] = *(const half8*)(Bb + r * BK + ((csx ^ (r & 7)) * 8));
            }
            #pragma unroll
            for (int mf = 0; mf < 4; ++mf)
                #pragma unroll
                for (int nf = 0; nf < 4; ++nf)
                    acc[mf][nf] = __builtin_amdgcn_mfma_f32_16x16x32_f16(
                        af[mf], bf[nf], acc[mf][nf], 0, 0, 0);
        }
    };

    LOADB(q0, s0, b0, 0);
    GLOADA(0, 0);
    DEQ(q0, s0, b0, 0);
    LOADB(q0, s0, b0, 1);
    __syncthreads();
    for (int kt = 0; kt < NKT; kt += 2) {
        GLOADA(1, kt + 1);
        if (kt + 2 < NKT) LOADB(q1, s1, b1, kt + 2);
        DEQ(q0, s0, b0, 1);
        COMPUTE(0);
        __syncthreads();
        if (kt + 2 < NKT) {
            GLOADA(0, kt + 2);
            if (kt + 3 < NKT) LOADB(q0, s0, b0, kt + 3);
            DEQ(q1, s1, b1, 0);
        }
        COMPUTE(1);
        if (kt + 2 < NKT) __syncthreads();
    }
    const int rb = bm * BM + wm + ((lane >> 4) << 2);
    const int cb = bn * BN + wn + (lane & 15);
    #pragma unroll
    for (int nf = 0; nf < 4; ++nf) {
        const int col = cb + nf * 16;
        const float lb = linb[col];
        #pragma unroll
        for (int mf = 0; mf < 4; ++mf) {
            const int row = rb + mf * 16;
            #pragma unroll
            for (int j = 0; j < 4; ++j)
                out[(size_t)(row + j) * N_DIM + col] = acc[mf][nf][j] + lb;
        }
    }
}

extern "C" void kernel_launch(void* const* d_in, const int* in_sizes, int n_in,
                              void* d_out, int out_size, void* d_ws, size_t ws_size,
                              hipStream_t stream) {
    const float*    x      = (const float*)d_in[0];
    const uint32_t* qw     = (const uint32_t*)d_in[1];
    const float*    scales = (const float*)d_in[2];
    const float*    biases = (const float*)d_in[3];
    const float*    linb   = (const float*)d_in[4];
    float*          out    = (float*)d_out;

    const int M = in_sizes[0] / K_DIM;                      // 8192
    const size_t XB = (size_t)M * K_DIM;                    // i8 bytes
    const size_t WB = (size_t)N_DIM * K_DIM;
    const size_t needQ = XB + WB + (size_t)(M + N_DIM) * 4;
    const size_t needF = (size_t)M * K_DIM * sizeof(_Float16);

    if (ws_size >= needQ && (M % 256) == 0) {
        int8_t* xqp = (int8_t*)d_ws;
        int8_t* wqp = xqp + XB;
        float*  sxp = (float*)(xqp + XB + WB);
        float*  swp = sxp + M;
        cvt_xq<<<M / 4, 256, 0, stream>>>(x, xqp, sxp);
        deq_wq<<<N_DIM / 4, 256, 0, stream>>>(qw, scales, biases, wqp, swp);
        dim3 grid((M / 256) * (N_DIM / 256));               // 32*43 = 1376
        qlin17<<<grid, 512, 0, stream>>>(xqp, wqp, sxp, swp, linb, out);
    } else if (ws_size >= needF && (M % BM) == 0) {
        _Float16* xh = (_Float16*)d_ws;
        cvt_x<<<(unsigned)((size_t)M * K_DIM / 8 / 256), 256, 0, stream>>>(x, xh);
        dim3 grid((M / BM) * (N_DIM / BN));
        qlin_f16<<<grid, 256, 0, stream>>>(xh, qw, scales, biases, linb, out);
    }
}